// Round 6
// baseline (231.926 us; speedup 1.0000x reference)
//
#include <hip/hip_runtime.h>
#include <math.h>

#define B_ 8
#define C_ 128
#define N_ 3136           // 56*56
#define MT 32             // m per tile (fused kernel)
#define QTBIG 128         // q rows per block
#define TILES32 98        // N_/MT
#define SPLIT_T 49        // tiles per split
#define QTILES 25         // ceil(N_/QTBIG)
#define PTILES 49         // prep: 64-m slices

typedef short bf16x8 __attribute__((ext_vector_type(8)));
typedef float f32x4 __attribute__((ext_vector_type(4)));

__device__ __forceinline__ unsigned short f2bf(float f) {
    union { float f; unsigned u; } x; x.f = f;
    return (unsigned short)((x.u + 0x8000u) >> 16);   // round-half-up to bf16
}

__device__ __forceinline__ void gl_lds16(const void* g, void* l) {
    __builtin_amdgcn_global_load_lds(
        (const __attribute__((address_space(1))) unsigned int*)g,
        (__attribute__((address_space(3))) unsigned int*)l, 16, 0, 0);
}

// ---------------------------------------------------------------------------
// colsum (standalone, fallback path only)
// ---------------------------------------------------------------------------
__global__ __launch_bounds__(256) void colsum_kernel(const float* __restrict__ s,
                                                     float* __restrict__ csum) {
    int blk = blockIdx.x;  // = b*C_ + c
    const float* p = s + (size_t)blk * N_;
    float acc = 0.f;
    for (int i = threadIdx.x; i < N_; i += 256) acc += p[i];
#pragma unroll
    for (int off = 32; off > 0; off >>= 1) acc += __shfl_down(acc, off, 64);
    __shared__ float part[4];
    if ((threadIdx.x & 63) == 0) part[threadIdx.x >> 6] = acc;
    __syncthreads();
    if (threadIdx.x == 0) csum[blk] = part[0] + part[1] + part[2] + part[3];
}

// ---------------------------------------------------------------------------
// Prepass (per (b, 64-m slice)):
//   sfT[b][m][c] bf16, 16B chunks XOR-swizzled by (m&15)      [+ colsum atomics]
//   qfT[b][c][m] bf16, 32-m groups, 16B chunks swizzled by (c&3)
// csum partials are exact fp32 (pre-conversion), atomicAdd-combined (csum
// zeroed by hipMemsetAsync each launch).
// ---------------------------------------------------------------------------
__global__ __launch_bounds__(256) void prep_kernel(const float* __restrict__ q,
                                                   const float* __restrict__ s,
                                                   unsigned short* __restrict__ sfT,
                                                   unsigned short* __restrict__ qfT,
                                                   float* __restrict__ csum) {
    __shared__ unsigned short T[8448];   // 16.5KB, reused by both phases
    const int tid = threadIdx.x, bid = blockIdx.x;
    const int b = bid & 7, m0 = (bid >> 3) * 64;
    const float* sb = s + (size_t)b * C_ * N_;
    const float* qb = q + (size_t)b * C_ * N_;

    // ---- phase A: sfT (c-major -> m-major) + colsum partials ----
    unsigned short (*TA)[132] = (unsigned short (*)[132])T;   // [64][132]
#pragma unroll
    for (int st = 0; st < 8; ++st) {
        int idx = st * 256 + tid;
        int c = idx >> 4, m4 = (idx & 15) * 4;
        float4 v = *(const float4*)&sb[(size_t)c * N_ + m0 + m4];
        TA[m4 + 0][c] = f2bf(v.x);
        TA[m4 + 1][c] = f2bf(v.y);
        TA[m4 + 2][c] = f2bf(v.z);
        TA[m4 + 3][c] = f2bf(v.w);
        float part = v.x + v.y + v.z + v.w;      // exact fp32 partial (4 m's)
        part += __shfl_xor(part, 1, 64);
        part += __shfl_xor(part, 2, 64);
        part += __shfl_xor(part, 4, 64);
        part += __shfl_xor(part, 8, 64);
        if ((tid & 15) == 0) atomicAdd(&csum[b * C_ + c], part);
    }
    __syncthreads();
    {
        unsigned short* dst = sfT + (size_t)b * N_ * C_;
#pragma unroll
        for (int st = 0; st < 4; ++st) {
            int g = st * 256 + tid;
            int mr = g >> 4, p = g & 15;
            int lch = p ^ (mr & 15);             // baked XOR swizzle
            const unsigned short* src = &TA[mr][lch * 8];
            ushort4 a = *(const ushort4*)src;
            ushort4 bq = *(const ushort4*)(src + 4);
            uint4 w;
            w.x = a.x | ((unsigned)a.y << 16);   w.y = a.z | ((unsigned)a.w << 16);
            w.z = bq.x | ((unsigned)bq.y << 16); w.w = bq.z | ((unsigned)bq.w << 16);
            *(uint4*)&dst[(size_t)(m0 + mr) * C_ + p * 8] = w;
        }
    }
    __syncthreads();   // T reuse

    // ---- phase B: qfT (n-major -> c-major), 32-m groups, swizzle by c&3 ----
    unsigned short (*TB)[66] = (unsigned short (*)[66])T;     // [128][66]
#pragma unroll
    for (int st = 0; st < 8; ++st) {
        int idx = st * 256 + tid;
        int r = idx >> 5, c4 = (idx & 31) * 4;
        float4 v = *(const float4*)&qb[(size_t)(m0 + r) * C_ + c4];
        TB[c4 + 0][r] = f2bf(v.x);
        TB[c4 + 1][r] = f2bf(v.y);
        TB[c4 + 2][r] = f2bf(v.z);
        TB[c4 + 3][r] = f2bf(v.w);
    }
    __syncthreads();
    {
        unsigned short* dst = qfT + (size_t)b * C_ * N_;
#pragma unroll
        for (int st = 0; st < 4; ++st) {
            int g = st * 256 + tid;
            int c = g >> 3, pp = g & 7;
            int grp = pp >> 2, p = pp & 3;       // 32-m group, chunk within
            int lch = p ^ (c & 3);
            const unsigned short* src = &TB[c][grp * 32 + lch * 8];
            ushort2 a0 = *(const ushort2*)(src);
            ushort2 a1 = *(const ushort2*)(src + 2);
            ushort2 a2 = *(const ushort2*)(src + 4);
            ushort2 a3 = *(const ushort2*)(src + 6);
            uint4 w;
            w.x = a0.x | ((unsigned)a0.y << 16); w.y = a1.x | ((unsigned)a1.y << 16);
            w.z = a2.x | ((unsigned)a2.y << 16); w.w = a3.x | ((unsigned)a3.y << 16);
            *(uint4*)&dst[(size_t)c * N_ + m0 + grp * 32 + p * 8] = w;
        }
    }
}

// ---------------------------------------------------------------------------
// m-split fused MFMA kernel + last-arriver epilogue. MT=32, LDS 32KB ->
// 3-4 blocks/CU. grid = 2 splits x 25 q-tiles x 8 batches = 400 blocks.
// P stays in registers (operand-swap + permuted-m; sigma(p) = (p>>2)*8 +
// (p&3) + ct*4 covers [0,32)). Both split blocks write raw partials; the
// SECOND arriver at the ws counter ((old&1)==1, valid under 0xAA even-base
// poison) reads the other half and writes final out0/out1.
// ---------------------------------------------------------------------------
__global__ __launch_bounds__(256, 3) void fused_split_kernel(
    const float* __restrict__ q, const float* __restrict__ s,
    const float* __restrict__ csum,
    const unsigned short* __restrict__ sfT,
    const unsigned short* __restrict__ qfT,
    float* __restrict__ Opart, float* __restrict__ dpart,
    int* __restrict__ cnt,
    float* __restrict__ out0, float* __restrict__ out1) {

    __shared__ __align__(16) unsigned short Kb[2][MT * C_];   // [m][c]  8KB x2
    __shared__ __align__(16) unsigned short Vb[2][C_ * MT];   // [c][m]  8KB x2
    __shared__ int flag_s;

    const int tid = threadIdx.x;
    const int lane = tid & 63;
    const int wave = tid >> 6;
    const int l15 = lane & 15;
    const int quad = lane >> 4;
    const int bid = blockIdx.x;
    const int b = bid & 7;                 // XCD-pinned batch
    const int rest = bid >> 3;             // 0..49
    const int qt = rest % QTILES;
    const int split = rest / QTILES;       // 0 or 1
    const int n0 = qt * QTBIG;
    const int t0 = split * SPLIT_T;

    const float* qb = q + (size_t)b * C_ * N_;
    const float* sb = s + (size_t)b * C_ * N_;
    const unsigned short* sfTb = sfT + (size_t)b * N_ * C_;
    const unsigned short* qfTb = qfT + (size_t)b * C_ * N_;

    const int sig_base = ((l15 >> 2) << 3) + (l15 & 3);   // permuted-m base

    // ---- prologue: async-stage tile t0 into buffer 0 ----
    {
        const size_t m1 = (size_t)t0 * MT;
#pragma unroll
        for (int j = 0; j < 2; ++j) {
            int i = j * 256 + tid;
            gl_lds16(sfTb + (m1 + (i >> 4)) * C_ + (i & 15) * 8,
                     &Kb[0][(j * 256 + wave * 64) * 8]);
            gl_lds16(qfTb + (size_t)(i >> 2) * N_ + m1 + (i & 3) * 8,
                     &Vb[0][(j * 256 + wave * 64) * 8]);
        }
    }

    // ---- Q fragments (registers for all tiles) ----
    bf16x8 qa[2][4];
#pragma unroll
    for (int rt = 0; rt < 2; ++rt) {
        int grow = n0 + wave * 32 + rt * 16 + l15;
        if (grow > N_ - 1) grow = N_ - 1;   // pad rows duplicate last row
#pragma unroll
        for (int ks = 0; ks < 4; ++ks) {
            int c0 = ks * 32 + quad * 8;
            float4 f0 = *(const float4*)&qb[(size_t)grow * C_ + c0];
            float4 f1 = *(const float4*)&qb[(size_t)grow * C_ + c0 + 4];
            union { unsigned short u[8]; bf16x8 v; } t;
            t.u[0] = f2bf(f0.x); t.u[1] = f2bf(f0.y);
            t.u[2] = f2bf(f0.z); t.u[3] = f2bf(f0.w);
            t.u[4] = f2bf(f1.x); t.u[5] = f2bf(f1.y);
            t.u[6] = f2bf(f1.z); t.u[7] = f2bf(f1.w);
            qa[rt][ks] = t.v;
        }
    }

    f32x4 O[2][8];
#pragma unroll
    for (int rt = 0; rt < 2; ++rt)
#pragma unroll
        for (int nt = 0; nt < 8; ++nt) O[rt][nt] = (f32x4){0.f, 0.f, 0.f, 0.f};
    float dsum[2] = {0.f, 0.f};

    for (int tt = 0; tt < SPLIT_T; ++tt) {
        const int cur = tt & 1;
        __syncthreads();   // staging for this tile complete; other buf free

        if (tt + 1 < SPLIT_T) {           // async-prefetch next tile
            const int nxt = cur ^ 1;
            const size_t m1 = (size_t)(t0 + tt + 1) * MT;
#pragma unroll
            for (int j = 0; j < 2; ++j) {
                int i = j * 256 + tid;
                gl_lds16(sfTb + (m1 + (i >> 4)) * C_ + (i & 15) * 8,
                         &Kb[nxt][(j * 256 + wave * 64) * 8]);
                gl_lds16(qfTb + (size_t)(i >> 2) * N_ + m1 + (i & 3) * 8,
                         &Vb[nxt][(j * 256 + wave * 64) * 8]);
            }
        }

        // ---- scoresT: acc[ct][rt], rows = permuted m, cols = q-rows ----
        f32x4 acc[2][2];
#pragma unroll
        for (int ct = 0; ct < 2; ++ct) {
            acc[ct][0] = (f32x4){0.f, 0.f, 0.f, 0.f};
            acc[ct][1] = (f32x4){0.f, 0.f, 0.f, 0.f};
            const int mrow = sig_base + ct * 4;
#pragma unroll
            for (int ks = 0; ks < 4; ++ks) {
                int ch = (ks * 4 + quad) ^ (mrow & 15);      // un-swizzle
                bf16x8 af = *(const bf16x8*)&Kb[cur][mrow * C_ + ch * 8];
                acc[ct][0] = __builtin_amdgcn_mfma_f32_16x16x32_bf16(af, qa[0][ks], acc[ct][0], 0, 0, 0);
                acc[ct][1] = __builtin_amdgcn_mfma_f32_16x16x32_bf16(af, qa[1][ks], acc[ct][1], 0, 0, 0);
            }
        }

        // ---- exp + in-lane pack: element j=ct*4+r -> m = quad*8+j ----
        bf16x8 pa[2];
#pragma unroll
        for (int rt = 0; rt < 2; ++rt) {
            union { unsigned short u[8]; bf16x8 v; } pk;
            float da = 0.f;
#pragma unroll
            for (int ct = 0; ct < 2; ++ct)
#pragma unroll
                for (int r = 0; r < 4; ++r) {
                    float e = __expf(acc[ct][rt][r]);
                    da += e;
                    pk.u[ct * 4 + r] = f2bf(e);
                }
            dsum[rt] += da;
            pa[rt] = pk.v;
        }

        // ---- PV: O[rt][nt] += P x V (one k=32 MFMA per nt) ----
#pragma unroll
        for (int nt = 0; nt < 8; ++nt) {
            const int crow = nt * 16 + l15;
            int ch = quad ^ (crow & 3);
            bf16x8 vf = *(const bf16x8*)&Vb[cur][crow * MT + ch * 8];
            O[0][nt] = __builtin_amdgcn_mfma_f32_16x16x32_bf16(pa[0], vf, O[0][nt], 0, 0, 0);
            O[1][nt] = __builtin_amdgcn_mfma_f32_16x16x32_bf16(pa[1], vf, O[1][nt], 0, 0, 0);
        }
    }

    // ---- split-partial denominator (quads hold disjoint m-octets) ----
#pragma unroll
    for (int rt = 0; rt < 2; ++rt) {
        float d = dsum[rt];
        d += __shfl_xor(d, 16, 64);
        d += __shfl_xor(d, 32, 64);
        dsum[rt] = d;                     // per-row (rt*16+l15), all lanes
        if (quad == 0) {
            int grow = n0 + wave * 32 + rt * 16 + l15;
            if (grow < N_)
                dpart[(size_t)(split * 8 + b) * N_ + grow] = d;
        }
    }

    // ---- write my raw partial O ----
#pragma unroll
    for (int rt = 0; rt < 2; ++rt)
#pragma unroll
        for (int r = 0; r < 4; ++r) {
            int grow = n0 + wave * 32 + rt * 16 + quad * 4 + r;
            if (grow < N_) {
                float* dst = Opart + ((size_t)(split * 8 + b) * N_ + grow) * C_;
#pragma unroll
                for (int nt = 0; nt < 8; ++nt)
                    dst[nt * 16 + l15] = O[rt][nt][r];
            }
        }

    // ---- last-arriver handshake ----
    __threadfence();
    __syncthreads();
    if (tid == 0) flag_s = atomicAdd(&cnt[b * QTILES + qt], 1);
    __syncthreads();
    if ((flag_s & 1) == 0) return;        // first arriver done
    __threadfence();                      // acquire: see other's partials

    // ---- winner epilogue: mask + normalize + residuals for 128 rows ----
    float* cs = (float*)&Kb[0][0];        // LDS reuse (tile loop done)
    float* mask_l = cs + C_;
    if (tid < C_) cs[tid] = csum[b * C_ + tid];
    __syncthreads();

    const int other = split ^ 1;
    const float* OthO = Opart + (size_t)(other * 8 + b) * N_ * C_;
    const float* Othd = dpart + (size_t)(other * 8 + b) * N_;
    const size_t bo = (size_t)b * C_ * N_;

#pragma unroll
    for (int rt = 0; rt < 2; ++rt)
#pragma unroll
        for (int r = 0; r < 4; ++r) {
            int row_l = wave * 32 + rt * 16 + quad * 4 + r;
            int grow = n0 + row_l;
            float myd = __shfl(dsum[rt], quad * 4 + r, 64);
            if (grow < N_) {
                float othd = Othd[grow];
                float qv[8];
                float dotp = 0.f;
#pragma unroll
                for (int nt = 0; nt < 8; ++nt) {
                    int col = nt * 16 + l15;
                    qv[nt] = qb[(size_t)grow * C_ + col];
                    dotp += qv[nt] * cs[col];
                }
                dotp += __shfl_xor(dotp, 1, 64);
                dotp += __shfl_xor(dotp, 2, 64);
                dotp += __shfl_xor(dotp, 4, 64);
                dotp += __shfl_xor(dotp, 8, 64);
                float mask = 1.0f / (1.0f + __expf(-dotp));
                if (l15 == 0) mask_l[row_l] = mask;
                float scl = mask / (myd + othd);
#pragma unroll
                for (int nt = 0; nt < 8; ++nt) {
                    int col = nt * 16 + l15;
                    float tot = O[rt][nt][r] + OthO[(size_t)grow * C_ + col];
                    out0[bo + (size_t)grow * C_ + col] = qv[nt] + tot * scl;
                }
            }
        }
    __syncthreads();   // mask_l complete

    // ---- out1 = s*(1+mask), coalesced ----
#pragma unroll
    for (int i = 0; i < 16; ++i) {
        int idx = i * 256 + tid;
        int row_l = idx >> 5, c4 = (idx & 31) * 4;
        int grow = n0 + row_l;
        if (grow < N_) {
            float4 sv = *(const float4*)&sb[(size_t)grow * C_ + c4];
            float om = 1.0f + mask_l[row_l];
            float4 o;
            o.x = sv.x * om; o.y = sv.y * om; o.z = sv.z * om; o.w = sv.w * om;
            *(float4*)&out1[bo + (size_t)grow * C_ + c4] = o;
        }
    }
}

// ---------------------------------------------------------------------------
// fp32 fallback kernel (only if ws_size too small).
// ---------------------------------------------------------------------------
__global__ __launch_bounds__(256, 2) void fused_kernel(const float* __restrict__ q,
                                                       const float* __restrict__ s,
                                                       const float* __restrict__ csum,
                                                       float* __restrict__ out0,
                                                       float* __restrict__ out1) {
    __shared__ float QtT[C_][68];
    __shared__ float Kt[C_ * 32];
    __shared__ float Vt[32 * C_];
    __shared__ float PT[32][68];
    __shared__ float mask_l[64];
    __shared__ float csum_l[C_];

    const int t = threadIdx.x;
    const int l = t & 63, w = t >> 6, tx = t & 15, ty = t >> 4;
    const int bid = blockIdx.x, b = bid & 7, n0 = (bid >> 3) * 64;
    const float* qb = q + (size_t)b * C_ * N_;
    const float* sb = s + (size_t)b * C_ * N_;

#pragma unroll
    for (int jj = 0; jj < 2; ++jj) {
        int c = l + 64 * jj;
#pragma unroll
        for (int i = 0; i < 16; ++i) QtT[c][w + 4 * i] = qb[(size_t)(n0 + w + 4 * i) * C_ + c];
    }
    if (t < C_) csum_l[t] = csum[b * C_ + t];
    __syncthreads();
    if (t < 64) {
        float d = 0.f;
        for (int c = 0; c < C_; ++c) d += QtT[c][t] * csum_l[c];
        mask_l[t] = 1.0f / (1.0f + __expf(-d));
    }
    float4 Oa[4], Ob[4];
#pragma unroll
    for (int i = 0; i < 4; ++i) { Oa[i] = make_float4(0,0,0,0); Ob[i] = make_float4(0,0,0,0); }
    float m_r[4], l_r[4];
#pragma unroll
    for (int i = 0; i < 4; ++i) { m_r[i] = -3.0e38f; l_r[i] = 0.f; }

    for (int mt = 0; mt < N_ / 32; ++mt) {
        const int m0 = mt * 32;
        __syncthreads();
#pragma unroll
        for (int i = 0; i < 4; ++i) {
            int s4 = (w * 4 + i) * 64 + l;
            int c = s4 >> 3, mq = (s4 & 7) * 4;
            *(float4*)&Kt[c * 32 + mq] = *(const float4*)&sb[(size_t)c * N_ + m0 + mq];
            *(float4*)&Vt[s4 * 4] = *(const float4*)&qb[(size_t)m0 * C_ + s4 * 4];
        }
        __syncthreads();
        float a[4][2];
#pragma unroll
        for (int i = 0; i < 4; ++i) a[i][0] = a[i][1] = 0.f;
#pragma unroll 4
        for (int k = 0; k < C_; ++k) {
            const float4 qv = *(const float4*)&QtT[k][4 * ty];
            const float2 kv = *(const float2*)&Kt[k * 32 + 2 * tx];
            a[0][0] = fmaf(qv.x, kv.x, a[0][0]); a[0][1] = fmaf(qv.x, kv.y, a[0][1]);
            a[1][0] = fmaf(qv.y, kv.x, a[1][0]); a[1][1] = fmaf(qv.y, kv.y, a[1][1]);
            a[2][0] = fmaf(qv.z, kv.x, a[2][0]); a[2][1] = fmaf(qv.z, kv.y, a[2][1]);
            a[3][0] = fmaf(qv.w, kv.x, a[3][0]); a[3][1] = fmaf(qv.w, kv.y, a[3][1]);
        }
#pragma unroll
        for (int i = 0; i < 4; ++i) {
            float tm = fmaxf(a[i][0], a[i][1]);
            tm = fmaxf(tm, __shfl_xor(tm, 1, 64)); tm = fmaxf(tm, __shfl_xor(tm, 2, 64));
            tm = fmaxf(tm, __shfl_xor(tm, 4, 64)); tm = fmaxf(tm, __shfl_xor(tm, 8, 64));
            float nm = fmaxf(m_r[i], tm);
            float al = __expf(m_r[i] - nm);
            m_r[i] = nm;
            float p0 = __expf(a[i][0] - nm), p1 = __expf(a[i][1] - nm);
            float ts = p0 + p1;
            ts += __shfl_xor(ts, 1, 64); ts += __shfl_xor(ts, 2, 64);
            ts += __shfl_xor(ts, 4, 64); ts += __shfl_xor(ts, 8, 64);
            l_r[i] = l_r[i] * al + ts;
            PT[2 * tx + 0][4 * ty + i] = p0;
            PT[2 * tx + 1][4 * ty + i] = p1;
            Oa[i].x *= al; Oa[i].y *= al; Oa[i].z *= al; Oa[i].w *= al;
            Ob[i].x *= al; Ob[i].y *= al; Ob[i].z *= al; Ob[i].w *= al;
        }
        __syncthreads();
#pragma unroll 2
        for (int j = 0; j < 32; ++j) {
            const float4 pv = *(const float4*)&PT[j][4 * ty];
            const float4 v0 = *(const float4*)&Vt[j * C_ + 4 * tx];
            const float4 v1 = *(const float4*)&Vt[j * C_ + 4 * tx + 64];
            Oa[0].x = fmaf(pv.x, v0.x, Oa[0].x); Oa[0].y = fmaf(pv.x, v0.y, Oa[0].y);
            Oa[0].z = fmaf(pv.x, v0.z, Oa[0].z); Oa[0].w = fmaf(pv.x, v0.w, Oa[0].w);
            Ob[0].x = fmaf(pv.x, v1.x, Ob[0].x); Ob[0].y = fmaf(pv.x, v1.y, Ob[0].y);
            Ob[0].z = fmaf(pv.x, v1.z, Ob[0].z); Ob[0].w = fmaf(pv.x, v1.w, Ob[0].w);
            Oa[1].x = fmaf(pv.y, v0.x, Oa[1].x); Oa[1].y = fmaf(pv.y, v0.y, Oa[1].y);
            Oa[1].z = fmaf(pv.y, v0.z, Oa[1].z); Oa[1].w = fmaf(pv.y, v0.w, Oa[1].w);
            Ob[1].x = fmaf(pv.y, v1.x, Ob[1].x); Ob[1].y = fmaf(pv.y, v1.y, Ob[1].y);
            Ob[1].z = fmaf(pv.y, v1.z, Ob[1].z); Ob[1].w = fmaf(pv.y, v1.w, Ob[1].w);
            Oa[2].x = fmaf(pv.z, v0.x, Oa[2].x); Oa[2].y = fmaf(pv.z, v0.y, Oa[2].y);
            Oa[2].z = fmaf(pv.z, v0.z, Oa[2].z); Oa[2].w = fmaf(pv.z, v0.w, Oa[2].w);
            Ob[2].x = fmaf(pv.z, v1.x, Ob[2].x); Ob[2].y = fmaf(pv.z, v1.y, Ob[2].y);
            Ob[2].z = fmaf(pv.z, v1.z, Ob[2].z); Ob[2].w = fmaf(pv.z, v1.w, Ob[2].w);
            Oa[3].x = fmaf(pv.w, v0.x, Oa[3].x); Oa[3].y = fmaf(pv.w, v0.y, Oa[3].y);
            Oa[3].z = fmaf(pv.w, v0.z, Oa[3].z); Oa[3].w = fmaf(pv.w, v0.w, Oa[3].w);
            Ob[3].x = fmaf(pv.w, v1.x, Ob[3].x); Ob[3].y = fmaf(pv.w, v1.y, Ob[3].y);
            Ob[3].z = fmaf(pv.w, v1.z, Ob[3].z); Ob[3].w = fmaf(pv.w, v1.w, Ob[3].w);
        }
    }
#pragma unroll
    for (int i = 0; i < 4; ++i) {
        const int r = 4 * ty + i;
        const float mk = mask_l[r];
        const float scl = mk / l_r[i];
        const float om = 1.0f + mk;
        const size_t row = (size_t)b * C_ * N_ + (size_t)(n0 + r) * C_;
#pragma unroll
        for (int h = 0; h < 2; ++h) {
            const int c = 4 * tx + 64 * h;
            const float4 ov = h ? Ob[i] : Oa[i];
            float4 qv = *(const float4*)&qb[(size_t)(n0 + r) * C_ + c];
            float4 sv = *(const float4*)&sb[(size_t)(n0 + r) * C_ + c];
            float4 o0, o1;
            o0.x = qv.x + ov.x * scl; o0.y = qv.y + ov.y * scl;
            o0.z = qv.z + ov.z * scl; o0.w = qv.w + ov.w * scl;
            o1.x = sv.x * om; o1.y = sv.y * om; o1.z = sv.z * om; o1.w = sv.w * om;
            *(float4*)&out0[row + c] = o0;
            *(float4*)&out1[row + c] = o1;
        }
    }
}

extern "C" void kernel_launch(void* const* d_in, const int* in_sizes, int n_in,
                              void* d_out, int out_size, void* d_ws, size_t ws_size,
                              hipStream_t stream) {
    const float* q = (const float*)d_in[0];
    const float* s = (const float*)d_in[1];
    float* out0 = (float*)d_out;
    float* out1 = out0 + (size_t)B_ * C_ * N_;
    float* csum = (float*)d_ws;                       // 4KB, zeroed below

    const size_t elems = (size_t)B_ * N_ * C_;        // 3.21M
    const size_t need = 4096
                      + 2 * elems * sizeof(unsigned short)   // sfT + qfT
                      + 2 * elems * sizeof(float)            // Opart (2 splits)
                      + 2 * (size_t)B_ * N_ * sizeof(float)  // dpart
                      + (size_t)B_ * QTILES * sizeof(int);   // counters

    if (ws_size >= need) {
        unsigned short* sfT = (unsigned short*)((char*)d_ws + 4096);
        unsigned short* qfT = sfT + elems;
        float* Opart = (float*)(qfT + elems);
        float* dpart = Opart + 2 * elems;
        int* cnt = (int*)(dpart + 2 * (size_t)B_ * N_);  // 0xAA-poisoned (even base) — winner = odd old
        hipMemsetAsync(csum, 0, B_ * C_ * sizeof(float), stream);
        prep_kernel<<<B_ * PTILES, 256, 0, stream>>>(q, s, sfT, qfT, csum);
        fused_split_kernel<<<2 * QTILES * B_, 256, 0, stream>>>(q, s, csum, sfT, qfT,
                                                                Opart, dpart, cnt, out0, out1);
    } else {
        colsum_kernel<<<B_ * C_, 256, 0, stream>>>(s, csum);
        fused_kernel<<<B_ * (N_ / 64), 256, 0, stream>>>(q, s, csum, out0, out1);
    }
}